// Round 4
// baseline (506.436 us; speedup 1.0000x reference)
//
#include <hip/hip_runtime.h>

typedef __attribute__((ext_vector_type(8))) short short8;
typedef __attribute__((ext_vector_type(4))) float f32x4;
typedef __attribute__((ext_vector_type(2))) unsigned u32x2;
typedef __attribute__((ext_vector_type(4))) unsigned long long ull4;

#define LOG2E 1.44269504f

__device__ __forceinline__ short f2bf(float f) {
  unsigned u = __builtin_bit_cast(unsigned, f);
  u += 0x7fffu + ((u >> 16) & 1u);   // round-to-nearest-even
  return (short)(u >> 16);
}

// ---------------- fused prologue + adj bit-pack ----------------
// z=0 plane (128x4 blocks): feat tile load -> Ax/Ay dots -> featB fragments
//   (+ WB pack on 8 blocks). Same as round 2.
// z=1 plane (128x4 blocks): adj bit-pack. Pure LINEAR stream of adj
//   (the pattern that runs at ~84% of HBM peak in this harness) ->
//   1 bit per entry via __ballot. adjP word layout: row stride 64 u64;
//   word jc*4+u covers j = jc*256 + u*64 + lane, bit `lane`.
__global__ __launch_bounds__(256) void gat_pro(
    const float* __restrict__ feat, const float* __restrict__ W,
    const float* __restrict__ a1, const float* __restrict__ a2,
    const int* __restrict__ adj,
    short* __restrict__ featB, short* __restrict__ WB,
    float* __restrict__ AxL, float* __restrict__ AyL,
    unsigned long long* __restrict__ adjP) {
  const int tid = threadIdx.x;
  const int f = blockIdx.x, b = blockIdx.y;

  if (blockIdx.z == 1) {
    // ---- adj bit-pack: rows f*32 + wv*8 .. +7 of batch b ----
    const int wv = tid >> 6, l = tid & 63;
#pragma unroll 1
    for (int r = 0; r < 8; ++r) {
      const int row = f * 32 + wv * 8 + r;
      const int* src = adj + ((size_t)(b * 4096 + row)) * 4096;
      unsigned long long* dst = adjP + ((size_t)(b * 4096 + row)) * 64;
#pragma unroll 4
      for (int jc = 0; jc < 16; ++jc) {
        unsigned long long m0 = __ballot(src[jc * 256 + 0 * 64 + l] > 0);
        unsigned long long m1 = __ballot(src[jc * 256 + 1 * 64 + l] > 0);
        unsigned long long m2 = __ballot(src[jc * 256 + 2 * 64 + l] > 0);
        unsigned long long m3 = __ballot(src[jc * 256 + 3 * 64 + l] > 0);
        if (l == 0) {
          ull4 mv = (ull4){m0, m1, m2, m3};
          *(ull4*)(dst + jc * 4) = mv;
        }
      }
    }
    return;
  }

  __shared__ __align__(16) float a1f[256], a2f[256];
  __shared__ __align__(16) float w1f[256], w2f[256];
  __shared__ __align__(16) float tile[32][260];

  a1f[tid] = a1[tid];
  a2f[tid] = a2[tid];
  __syncthreads();

  {
    float s1 = 0.f, s2 = 0.f;
    const float4* wr = (const float4*)(W + (size_t)tid * 256);
    for (int d0 = 0; d0 < 64; ++d0) {
      float4 v = wr[d0];
      s1 += v.x * a1f[d0 * 4] + v.y * a1f[d0 * 4 + 1] + v.z * a1f[d0 * 4 + 2] + v.w * a1f[d0 * 4 + 3];
      s2 += v.x * a2f[d0 * 4] + v.y * a2f[d0 * 4 + 1] + v.z * a2f[d0 * 4 + 2] + v.w * a2f[d0 * 4 + 3];
    }
    w1f[tid] = s1;
    w2f[tid] = s2;
  }
  __syncthreads();

  {
    const int r = tid >> 3, g8 = tid & 7;
    const float* frow = feat + ((size_t)(b * 4096 + f * 32 + r)) * 256;
    float s1 = 0.f, s2 = 0.f;
#pragma unroll
    for (int k = 0; k < 8; ++k) {
      const int c4 = g8 + 8 * k;
      float4 v = *(const float4*)(frow + c4 * 4);
      float4 u1 = *(const float4*)&w1f[c4 * 4];
      float4 u2 = *(const float4*)&w2f[c4 * 4];
      s1 += v.x * u1.x + v.y * u1.y + v.z * u1.z + v.w * u1.w;
      s2 += v.x * u2.x + v.y * u2.y + v.z * u2.z + v.w * u2.w;
      *(float4*)&tile[r][c4 * 4] = v;
    }
#pragma unroll
    for (int off = 4; off >= 1; off >>= 1) {
      s1 += __shfl_xor(s1, off);
      s2 += __shfl_xor(s2, off);
    }
    if (g8 == 0) {
      AxL[b * 4096 + f * 32 + r] = s1 * LOG2E;
      AyL[b * 4096 + f * 32 + r] = s2 * LOG2E;
    }
  }
  __syncthreads();

  {
    const int g = tid >> 4, l15 = tid & 15;
    short* d = featB + (((size_t)((b * 128 + f) * 16 + g)) * 64) * 8;
#pragma unroll
    for (int q = 0; q < 4; ++q) {
      short8 v;
#pragma unroll
      for (int j8 = 0; j8 < 8; ++j8) v[j8] = f2bf(tile[q * 8 + j8][g * 16 + l15]);
      *(short8*)(d + (q * 16 + l15) * 8) = v;
    }
  }

  if (b == 0 && f < 8) {
    const int g = tid >> 4, l15 = tid & 15;
    const float* s = W + ((size_t)f * 32) * 256 + g * 16 + l15;
    short* d = WB + (((size_t)(f * 16 + g)) * 64) * 8;
#pragma unroll
    for (int q = 0; q < 4; ++q) {
      short8 v;
#pragma unroll
      for (int j8 = 0; j8 < 8; ++j8) v[j8] = f2bf(s[(q * 8 + j8) * 256]);
      *(short8*)(d + (q * 16 + l15) * 8) = v;
    }
  }
}

// -------- fused softmax(mask(lrelu(rank1)))@feat @W +ELU --------
// Round-2 structure (best measured), with adj replaced by the bit-packed
// mask: phase-1 no longer touches HBM (bitmask is ~2 MB/batch, L2-hot),
// so the vmcnt(0)-at-barrier drain has nothing expensive to drain and the
// kernel becomes compute-bound (MFMA + exp2). 64-row blocks, each wave
// owns two row-groups + one col-group (featB fragment feeds 2 MFMAs).
// Lane l's bits for window w, row k: u64 word adjP[row*64 + w*4 + (l>>4)],
// bit (l&15)*4 + u for j = w*256 + 4l + u.
__global__ __launch_bounds__(512, 2) void gat_attn(
    const short* __restrict__ featB,  // [4][128][16][64][8] bf16 fragments
    const unsigned long long* __restrict__ adjP,  // [4][4096][64] bitmask
    const float* __restrict__ AxL, const float* __restrict__ AyL,
    const short* __restrict__ WB,     // [8][16][64][8] bf16 fragments
    float* __restrict__ out)          // [4][4096][256] f32
{
  __shared__ short smem[33792];  // Pbuf[2][64][264]; later aliased as hbuf[64][264]
  __shared__ float mred[8];

  const int tid = threadIdx.x;
  const int blk = blockIdx.x;
  const int x = blk & 7;
  const int b = x >> 1;                       // XCD-pinned batch
  const int it = ((blk >> 3) << 1) | (x & 1); // 0..63
  const int i0 = it << 6;
  const int scoff = (blk >> 3) & 15;          // staggered j-window start

  const int lane = tid & 63;
  const int aw = tid >> 6;                    // wave 0..7

  // ---- per-batch max of AxL ----
  const float* axb = AxL + b * 4096;
  float mx = -3.4e38f;
  for (int i = tid; i < 4096; i += 512) mx = fmaxf(mx, axb[i]);
#pragma unroll
  for (int off = 32; off >= 1; off >>= 1) mx = fmaxf(mx, __shfl_xor(mx, off));
  if (lane == 0) mred[aw] = mx;
  __syncthreads();
  const float MbLb = fmaxf(fmaxf(fmaxf(mred[0], mred[1]), fmaxf(mred[2], mred[3])),
                           fmaxf(fmaxf(mred[4], mred[5]), fmaxf(mred[6], mred[7])));

  // --- P-producer role: wave owns rows aw*8..aw*8+7; lane owns 4 j's ---
  float aLk[8], ddk[8];
#pragma unroll
  for (int k = 0; k < 8; ++k) {
    float ayL = AyL[b * 4096 + i0 + aw * 8 + k];
    float sL = ayL + MbLb;
    float mrL = fmaxf(sL, 0.2f * sL);
    aLk[k] = ayL - mrL;
    ddk[k] = -0.8f * mrL;
  }
  const unsigned long long* adjPr =
      adjP + ((size_t)(b * 4096 + i0 + aw * 8)) * 64 + (lane >> 4);
  const float4* axp = (const float4*)(AxL + b * 4096) + lane;
  const int sh = (lane & 15) * 4;

  // --- MFMA role: wave = (row-group pair, col-group) ---
  const int rowg = (aw & 1) << 4;    // 0/16; second group is +32
  const int cgrp = (aw >> 1) << 2;   // col-group base in 16-col units: 0,4,8,12
  const int l15 = lane & 15;
  const int q = lane >> 4;

  f32x4 acc[2][4], lac[2];
#pragma unroll
  for (int r = 0; r < 2; ++r) {
    lac[r] = (f32x4){0.f, 0.f, 0.f, 0.f};
#pragma unroll
    for (int j = 0; j < 4; ++j) acc[r][j] = (f32x4){0.f, 0.f, 0.f, 0.f};
  }

  short8 ones;
#pragma unroll
  for (int j = 0; j < 8; ++j) ones[j] = (short)0x3F80;  // bf16 1.0

  const short* fbb = featB + (size_t)b * 128 * 16 * 64 * 8 + lane * 8;

  unsigned long long adv[8];
  float4 axv;
  {
    const int w0 = scoff;
    axv = axp[w0 * 64];
#pragma unroll
    for (int k = 0; k < 8; ++k) adv[k] = adjPr[(size_t)k * 64 + w0 * 4];
  }

  for (int sc = 0; sc < 16; ++sc) {
    const int wsc = (scoff + sc) & 15;        // actual j-window this iteration
    const int pb = (sc & 1) * 16896;
    // ---- phase 1: 32 probs (8 rows x 4 j) -> Pbuf ----
    {
      const float* af = (const float*)&axv;
#pragma unroll
      for (int k = 0; k < 8; ++k) {
        unsigned pr[4];
#pragma unroll
        for (int u = 0; u < 4; ++u) {
          float v = af[u] + aLk[k];
          float uu = fmaxf(v, fmaf(0.2f, v, ddk[k]));
          unsigned ub = ((adv[k] >> (sh + u)) & 1ull)
                            ? __builtin_bit_cast(unsigned, uu) : 0xFF800000u;
          float p = __builtin_amdgcn_exp2f(__builtin_bit_cast(float, ub));
          pr[u] = __builtin_bit_cast(unsigned, p) + 0x8000u;
        }
        u32x2 pw;
        pw[0] = __builtin_amdgcn_perm(pr[1], pr[0], 0x07060302u);
        pw[1] = __builtin_amdgcn_perm(pr[3], pr[2], 0x07060302u);
        *(u32x2*)(smem + pb + (aw * 8 + k) * 264 + lane * 4) = pw;
      }
    }
    __syncthreads();

    // ---- prefetch next window's bits (L2-hot, tiny) + Ax ----
    if (sc < 15) {
      const int wn = (scoff + sc + 1) & 15;
      axv = axp[wn * 64];
#pragma unroll
      for (int k = 0; k < 8; ++k) adv[k] = adjPr[(size_t)k * 64 + wn * 4];
    }

    // ---- phase 2: 8 k-steps; each B fragment feeds both row-groups ----
#pragma unroll
    for (int h = 0; h < 8; ++h) {
      const int f = wsc * 8 + h;
      const short* fb = fbb + (((size_t)f * 16 + cgrp) << 9);
      short8 a0 = *(const short8*)(smem + pb + (rowg + l15) * 264 + h * 32 + q * 8);
      short8 a1 = *(const short8*)(smem + pb + (rowg + 32 + l15) * 264 + h * 32 + q * 8);
      lac[0] = __builtin_amdgcn_mfma_f32_16x16x32_bf16(a0, ones, lac[0], 0, 0, 0);
      lac[1] = __builtin_amdgcn_mfma_f32_16x16x32_bf16(a1, ones, lac[1], 0, 0, 0);
#pragma unroll
      for (int ct = 0; ct < 4; ++ct) {
        short8 bf = *(const short8*)(fb + (ct << 9));
        acc[0][ct] = __builtin_amdgcn_mfma_f32_16x16x32_bf16(a0, bf, acc[0][ct], 0, 0, 0);
        acc[1][ct] = __builtin_amdgcn_mfma_f32_16x16x32_bf16(a1, bf, acc[1][ct], 0, 0, 0);
      }
    }
  }

  // lac[r][reg] = row-sum for row rowg + r*32 + q*4 + reg (C/D layout)
  float linv[2][4];
#pragma unroll
  for (int r = 0; r < 2; ++r)
#pragma unroll
    for (int reg = 0; reg < 4; ++reg) {
      float l = lac[r][reg];
      linv[r][reg] = l > 0.f ? 1.f / l : 0.f;
    }

  __syncthreads();   // all Pbuf reads done before aliasing smem as hbuf
  short* hbuf = smem;  // [64][264]
#pragma unroll
  for (int r = 0; r < 2; ++r)
#pragma unroll
    for (int reg = 0; reg < 4; ++reg) {
      const int lr = rowg + r * 32 + q * 4 + reg;
#pragma unroll
      for (int ct = 0; ct < 4; ++ct)
        hbuf[lr * 264 + cgrp * 16 + ct * 16 + l15] = f2bf(acc[r][ct][reg] * linv[r][reg]);
    }
  __syncthreads();

  // ---- epilogue GEMM: (64x256) @ W, ELU, store; WB frags coalesced ----
  f32x4 ac2[2][4];
#pragma unroll
  for (int r = 0; r < 2; ++r)
#pragma unroll
    for (int j = 0; j < 4; ++j) ac2[r][j] = (f32x4){0.f, 0.f, 0.f, 0.f};

  const short* wbb = WB + lane * 8;
#pragma unroll
  for (int f = 0; f < 8; ++f) {
    short8 a0 = *(const short8*)&hbuf[(rowg + l15) * 264 + f * 32 + q * 8];
    short8 a1 = *(const short8*)&hbuf[(rowg + 32 + l15) * 264 + f * 32 + q * 8];
    const short* wb = wbb + (((size_t)f * 16 + cgrp) << 9);
#pragma unroll
    for (int ct = 0; ct < 4; ++ct) {
      short8 bf = *(const short8*)(wb + (ct << 9));
      ac2[0][ct] = __builtin_amdgcn_mfma_f32_16x16x32_bf16(a0, bf, ac2[0][ct], 0, 0, 0);
      ac2[1][ct] = __builtin_amdgcn_mfma_f32_16x16x32_bf16(a1, bf, ac2[1][ct], 0, 0, 0);
    }
  }

#pragma unroll
  for (int r = 0; r < 2; ++r)
#pragma unroll
    for (int reg = 0; reg < 4; ++reg) {
      const int row = i0 + rowg + r * 32 + q * 4 + reg;
      float* orow = out + ((size_t)(b * 4096 + row)) * 256 + cgrp * 16 + l15;
#pragma unroll
      for (int ct = 0; ct < 4; ++ct) {
        float v = ac2[r][ct][reg];
        float o = v > 0.f ? v : (__builtin_amdgcn_exp2f(v * LOG2E) - 1.f);
        __builtin_nontemporal_store(o, orow + ct * 16);
      }
    }
}

extern "C" void kernel_launch(void* const* d_in, const int* in_sizes, int n_in,
                              void* d_out, int out_size, void* d_ws, size_t ws_size,
                              hipStream_t stream) {
  (void)in_sizes; (void)n_in; (void)out_size; (void)ws_size;
  const float* feat = (const float*)d_in[0];
  const int* adj = (const int*)d_in[1];
  const float* W = (const float*)d_in[2];
  const float* a1 = (const float*)d_in[3];
  const float* a2 = (const float*)d_in[4];
  float* out = (float*)d_out;

  char* ws = (char*)d_ws;
  short* featB = (short*)ws;                              // 8,388,608 B
  short* WB    = (short*)(ws + 8388608);                  // 131,072 B
  float* AxL   = (float*)(ws + 8519680);                  // 65,536 B
  float* AyL   = (float*)(ws + 8585216);                  // 65,536 B
  unsigned long long* adjP = (unsigned long long*)(ws + 8650752);  // 8,388,608 B

  hipLaunchKernelGGL(gat_pro, dim3(128, 4, 2), dim3(256), 0, stream,
                     feat, W, a1, a2, adj, featB, WB, AxL, AyL, adjP);
  hipLaunchKernelGGL(gat_attn, dim3(256), dim3(512), 0, stream,
                     featB, adjP, AxL, AyL, WB, out);
}

// Round 5
// 434.793 us; speedup vs baseline: 1.1648x; 1.1648x over previous
//
#include <hip/hip_runtime.h>

typedef __attribute__((ext_vector_type(8))) short short8;
typedef __attribute__((ext_vector_type(4))) float f32x4;
typedef __attribute__((ext_vector_type(4))) int i32x4;
typedef __attribute__((ext_vector_type(2))) unsigned u32x2;

#define LOG2E 1.44269504f

__device__ __forceinline__ short f2bf(float f) {
  unsigned u = __builtin_bit_cast(unsigned, f);
  u += 0x7fffu + ((u >> 16) & 1u);   // round-to-nearest-even
  return (short)(u >> 16);
}

// ---------------- fused prologue (round-2 version, reverted) ----------------
__global__ __launch_bounds__(256) void gat_pro(
    const float* __restrict__ feat, const float* __restrict__ W,
    const float* __restrict__ a1, const float* __restrict__ a2,
    short* __restrict__ featB, short* __restrict__ WB,
    float* __restrict__ AxL, float* __restrict__ AyL) {
  __shared__ __align__(16) float a1f[256], a2f[256];
  __shared__ __align__(16) float w1f[256], w2f[256];
  __shared__ __align__(16) float tile[32][260];
  const int tid = threadIdx.x;
  const int f = blockIdx.x, b = blockIdx.y;

  a1f[tid] = a1[tid];
  a2f[tid] = a2[tid];
  __syncthreads();

  {
    float s1 = 0.f, s2 = 0.f;
    const float4* wr = (const float4*)(W + (size_t)tid * 256);
    for (int d0 = 0; d0 < 64; ++d0) {
      float4 v = wr[d0];
      s1 += v.x * a1f[d0 * 4] + v.y * a1f[d0 * 4 + 1] + v.z * a1f[d0 * 4 + 2] + v.w * a1f[d0 * 4 + 3];
      s2 += v.x * a2f[d0 * 4] + v.y * a2f[d0 * 4 + 1] + v.z * a2f[d0 * 4 + 2] + v.w * a2f[d0 * 4 + 3];
    }
    w1f[tid] = s1;
    w2f[tid] = s2;
  }
  __syncthreads();

  {
    const int r = tid >> 3, g8 = tid & 7;
    const float* frow = feat + ((size_t)(b * 4096 + f * 32 + r)) * 256;
    float s1 = 0.f, s2 = 0.f;
#pragma unroll
    for (int k = 0; k < 8; ++k) {
      const int c4 = g8 + 8 * k;
      float4 v = *(const float4*)(frow + c4 * 4);
      float4 u1 = *(const float4*)&w1f[c4 * 4];
      float4 u2 = *(const float4*)&w2f[c4 * 4];
      s1 += v.x * u1.x + v.y * u1.y + v.z * u1.z + v.w * u1.w;
      s2 += v.x * u2.x + v.y * u2.y + v.z * u2.z + v.w * u2.w;
      *(float4*)&tile[r][c4 * 4] = v;
    }
#pragma unroll
    for (int off = 4; off >= 1; off >>= 1) {
      s1 += __shfl_xor(s1, off);
      s2 += __shfl_xor(s2, off);
    }
    if (g8 == 0) {
      AxL[b * 4096 + f * 32 + r] = s1 * LOG2E;
      AyL[b * 4096 + f * 32 + r] = s2 * LOG2E;
    }
  }
  __syncthreads();

  {
    const int g = tid >> 4, l15 = tid & 15;
    short* d = featB + (((size_t)((b * 128 + f) * 16 + g)) * 64) * 8;
#pragma unroll
    for (int q = 0; q < 4; ++q) {
      short8 v;
#pragma unroll
      for (int j8 = 0; j8 < 8; ++j8) v[j8] = f2bf(tile[q * 8 + j8][g * 16 + l15]);
      *(short8*)(d + (q * 16 + l15) * 8) = v;
    }
  }

  if (b == 0 && f < 8) {
    const int g = tid >> 4, l15 = tid & 15;
    const float* s = W + ((size_t)f * 32) * 256 + g * 16 + l15;
    short* d = WB + (((size_t)(f * 16 + g)) * 64) * 8;
#pragma unroll
    for (int q = 0; q < 4; ++q) {
      short8 v;
#pragma unroll
      for (int j8 = 0; j8 < 8; ++j8) v[j8] = f2bf(s[(q * 8 + j8) * 256]);
      *(short8*)(d + (q * 16 + l15) * 8) = v;
    }
  }
}

// -------- fused softmax(mask(lrelu(rank1)))@feat @W +ELU --------
// Round-2 structure (best measured: 429 us total) with ONE change:
// paired-window adj prefetch. Every other superstep a wave issues BOTH the
// next two windows' adj loads back-to-back; the two 1 KB chunks per row are
// address-adjacent (windows w, w+1 are contiguous columns) AND
// time-adjacent -> 2 KB sequential DRAM bursts per row instead of isolated
// 1 KB touches a full superstep apart -> better page-hit rate on the
// 268 MB adj stream (the modeled bottleneck pipe: 64 KB/CU/superstep at
// fair-share HBM BW = ~6400 cyc, vs ~2k cyc for compute phases).
// sc loop unrolled 2x so advA/advB indexing is compile-time (rule #20).
__global__ __launch_bounds__(512, 2) void gat_attn(
    const short* __restrict__ featB,  // [4][128][16][64][8] bf16 fragments
    const int* __restrict__ adj,      // [4][4096][4096]
    const float* __restrict__ AxL, const float* __restrict__ AyL,
    const short* __restrict__ WB,     // [8][16][64][8] bf16 fragments
    float* __restrict__ out)          // [4][4096][256] f32
{
  __shared__ short smem[33792];  // Pbuf[2][64][264]; later aliased as hbuf[64][264]
  __shared__ float mred[8];

  const int tid = threadIdx.x;
  const int blk = blockIdx.x;
  const int x = blk & 7;
  const int b = x >> 1;                       // XCD-pinned batch
  const int it = ((blk >> 3) << 1) | (x & 1); // 0..63
  const int i0 = it << 6;
  const int scoff = (blk >> 3) & 15;          // staggered j-window start

  const int lane = tid & 63;
  const int aw = tid >> 6;                    // wave 0..7

  // ---- per-batch max of AxL ----
  const float* axb = AxL + b * 4096;
  float mx = -3.4e38f;
  for (int i = tid; i < 4096; i += 512) mx = fmaxf(mx, axb[i]);
#pragma unroll
  for (int off = 32; off >= 1; off >>= 1) mx = fmaxf(mx, __shfl_xor(mx, off));
  if (lane == 0) mred[aw] = mx;
  __syncthreads();
  const float MbLb = fmaxf(fmaxf(fmaxf(mred[0], mred[1]), fmaxf(mred[2], mred[3])),
                           fmaxf(fmaxf(mred[4], mred[5]), fmaxf(mred[6], mred[7])));

  // --- P-producer role: wave owns rows aw*8..aw*8+7; lane owns 4 j's ---
  float aLk[8], ddk[8];
#pragma unroll
  for (int k = 0; k < 8; ++k) {
    float ayL = AyL[b * 4096 + i0 + aw * 8 + k];
    float sL = ayL + MbLb;
    float mrL = fmaxf(sL, 0.2f * sL);
    aLk[k] = ayL - mrL;
    ddk[k] = -0.8f * mrL;
  }
  const int* adjr = adj + ((size_t)(b * 4096 + i0 + aw * 8)) * 4096 + lane * 4;
  const float4* axp = (const float4*)(AxL + b * 4096) + lane;

  // --- MFMA role: wave = (row-group pair, col-group) ---
  const int rowg = (aw & 1) << 4;    // 0/16; second group is +32
  const int cgrp = (aw >> 1) << 2;   // col-group base in 16-col units: 0,4,8,12
  const int l15 = lane & 15;
  const int q = lane >> 4;

  f32x4 acc[2][4], lac[2];
#pragma unroll
  for (int r = 0; r < 2; ++r) {
    lac[r] = (f32x4){0.f, 0.f, 0.f, 0.f};
#pragma unroll
    for (int j = 0; j < 4; ++j) acc[r][j] = (f32x4){0.f, 0.f, 0.f, 0.f};
  }

  short8 ones;
#pragma unroll
  for (int j = 0; j < 8; ++j) ones[j] = (short)0x3F80;  // bf16 1.0

  const short* fbb = featB + (size_t)b * 128 * 16 * 64 * 8 + lane * 8;

  i32x4 advA[8], advB[8];
  float4 axv;

  // paired adj load: windows wA, wB -> per row, two 1 KB chunks issued
  // back-to-back (contiguous 2 KB when wB == wA+1, i.e. all but the wrap)
  auto loadAdjPair = [&](int wA, int wB) {
#pragma unroll
    for (int k = 0; k < 8; ++k) {
      advA[k] = __builtin_nontemporal_load((const i32x4*)(adjr) + (size_t)k * 1024 + wA * 64);
      advB[k] = __builtin_nontemporal_load((const i32x4*)(adjr) + (size_t)k * 1024 + wB * 64);
    }
  };

  // phase 1 for superstep sc using window data advU
  auto phase1 = [&](int sc, const i32x4 (&advU)[8]) {
    const int pb = (sc & 1) * 16896;
    const float* af = (const float*)&axv;
#pragma unroll
    for (int k = 0; k < 8; ++k) {
      unsigned pr[4];
#pragma unroll
      for (int u = 0; u < 4; ++u) {
        float v = af[u] + aLk[k];
        float uu = fmaxf(v, fmaf(0.2f, v, ddk[k]));
        unsigned ub = advU[k][u] > 0 ? __builtin_bit_cast(unsigned, uu) : 0xFF800000u;
        float p = __builtin_amdgcn_exp2f(__builtin_bit_cast(float, ub));
        pr[u] = __builtin_bit_cast(unsigned, p) + 0x8000u;
      }
      u32x2 pw;
      pw[0] = __builtin_amdgcn_perm(pr[1], pr[0], 0x07060302u);
      pw[1] = __builtin_amdgcn_perm(pr[3], pr[2], 0x07060302u);
      *(u32x2*)(smem + pb + (aw * 8 + k) * 264 + lane * 4) = pw;
    }
  };

  // phase 2 for superstep sc (8 k-steps; each B fragment feeds both row-groups)
  auto phase2 = [&](int sc) {
    const int wsc = (scoff + sc) & 15;
    const int pb = (sc & 1) * 16896;
#pragma unroll
    for (int h = 0; h < 8; ++h) {
      const int f = wsc * 8 + h;
      const short* fb = fbb + (((size_t)f * 16 + cgrp) << 9);
      short8 a0 = *(const short8*)(smem + pb + (rowg + l15) * 264 + h * 32 + q * 8);
      short8 a1 = *(const short8*)(smem + pb + (rowg + 32 + l15) * 264 + h * 32 + q * 8);
      lac[0] = __builtin_amdgcn_mfma_f32_16x16x32_bf16(a0, ones, lac[0], 0, 0, 0);
      lac[1] = __builtin_amdgcn_mfma_f32_16x16x32_bf16(a1, ones, lac[1], 0, 0, 0);
#pragma unroll
      for (int ct = 0; ct < 4; ++ct) {
        short8 bf = *(const short8*)(fb + (ct << 9));
        acc[0][ct] = __builtin_amdgcn_mfma_f32_16x16x32_bf16(a0, bf, acc[0][ct], 0, 0, 0);
        acc[1][ct] = __builtin_amdgcn_mfma_f32_16x16x32_bf16(a1, bf, acc[1][ct], 0, 0, 0);
      }
    }
  };

  // ---- pre-loop: windows scoff, scoff+1 ----
  loadAdjPair(scoff, (scoff + 1) & 15);
  axv = axp[scoff * 64];

  // ---- main loop, unrolled 2x (even sc -> advA, odd sc -> advB) ----
  for (int scp = 0; scp < 8; ++scp) {
    {
      const int sc = 2 * scp;
      phase1(sc, advA);
      __syncthreads();
      axv = axp[((scoff + sc + 1) & 15) * 64];
      phase2(sc);
    }
    {
      const int sc = 2 * scp + 1;
      phase1(sc, advB);
      __syncthreads();
      if (sc < 15) {
        axv = axp[((scoff + sc + 1) & 15) * 64];
        // prefetch the NEXT pair of windows (sc+1, sc+2) back-to-back
        loadAdjPair((scoff + sc + 1) & 15, (scoff + sc + 2) & 15);
      }
      phase2(sc);
    }
  }

  // lac[r][reg] = row-sum for row rowg + r*32 + q*4 + reg (C/D layout)
  float linv[2][4];
#pragma unroll
  for (int r = 0; r < 2; ++r)
#pragma unroll
    for (int reg = 0; reg < 4; ++reg) {
      float l = lac[r][reg];
      linv[r][reg] = l > 0.f ? 1.f / l : 0.f;
    }

  __syncthreads();   // all Pbuf reads done before aliasing smem as hbuf
  short* hbuf = smem;  // [64][264]
#pragma unroll
  for (int r = 0; r < 2; ++r)
#pragma unroll
    for (int reg = 0; reg < 4; ++reg) {
      const int lr = rowg + r * 32 + q * 4 + reg;
#pragma unroll
      for (int ct = 0; ct < 4; ++ct)
        hbuf[lr * 264 + cgrp * 16 + ct * 16 + l15] = f2bf(acc[r][ct][reg] * linv[r][reg]);
    }
  __syncthreads();

  // ---- epilogue GEMM: (64x256) @ W, ELU, store; WB frags coalesced ----
  f32x4 ac2[2][4];
#pragma unroll
  for (int r = 0; r < 2; ++r)
#pragma unroll
    for (int j = 0; j < 4; ++j) ac2[r][j] = (f32x4){0.f, 0.f, 0.f, 0.f};

  const short* wbb = WB + lane * 8;
#pragma unroll
  for (int f = 0; f < 8; ++f) {
    short8 a0 = *(const short8*)&hbuf[(rowg + l15) * 264 + f * 32 + q * 8];
    short8 a1 = *(const short8*)&hbuf[(rowg + 32 + l15) * 264 + f * 32 + q * 8];
    const short* wb = wbb + (((size_t)f * 16 + cgrp) << 9);
#pragma unroll
    for (int ct = 0; ct < 4; ++ct) {
      short8 bf = *(const short8*)(wb + (ct << 9));
      ac2[0][ct] = __builtin_amdgcn_mfma_f32_16x16x32_bf16(a0, bf, ac2[0][ct], 0, 0, 0);
      ac2[1][ct] = __builtin_amdgcn_mfma_f32_16x16x32_bf16(a1, bf, ac2[1][ct], 0, 0, 0);
    }
  }

#pragma unroll
  for (int r = 0; r < 2; ++r)
#pragma unroll
    for (int reg = 0; reg < 4; ++reg) {
      const int row = i0 + rowg + r * 32 + q * 4 + reg;
      float* orow = out + ((size_t)(b * 4096 + row)) * 256 + cgrp * 16 + l15;
#pragma unroll
      for (int ct = 0; ct < 4; ++ct) {
        float v = ac2[r][ct][reg];
        float o = v > 0.f ? v : (__builtin_amdgcn_exp2f(v * LOG2E) - 1.f);
        __builtin_nontemporal_store(o, orow + ct * 16);
      }
    }
}

extern "C" void kernel_launch(void* const* d_in, const int* in_sizes, int n_in,
                              void* d_out, int out_size, void* d_ws, size_t ws_size,
                              hipStream_t stream) {
  (void)in_sizes; (void)n_in; (void)out_size; (void)ws_size;
  const float* feat = (const float*)d_in[0];
  const int* adj = (const int*)d_in[1];
  const float* W = (const float*)d_in[2];
  const float* a1 = (const float*)d_in[3];
  const float* a2 = (const float*)d_in[4];
  float* out = (float*)d_out;

  char* ws = (char*)d_ws;
  short* featB   = (short*)ws;                     // 4*128*16*64*8*2 = 8,388,608 B
  short* WB      = (short*)(ws + 8388608);         // 131,072 B
  float* AxL     = (float*)(ws + 8519680);         // 64 KB
  float* AyL     = (float*)(ws + 8585216);         // 64 KB

  hipLaunchKernelGGL(gat_pro, dim3(128, 4), dim3(256), 0, stream, feat, W, a1, a2, featB, WB, AxL, AyL);
  hipLaunchKernelGGL(gat_attn, dim3(256), dim3(512), 0, stream, featB, adj, AxL, AyL, WB, out);
}

// Round 6
// 410.041 us; speedup vs baseline: 1.2351x; 1.0604x over previous
//
#include <hip/hip_runtime.h>

typedef __attribute__((ext_vector_type(8))) short short8;
typedef __attribute__((ext_vector_type(4))) float f32x4;
typedef __attribute__((ext_vector_type(4))) int i32x4;
typedef __attribute__((ext_vector_type(2))) unsigned u32x2;

#define LOG2E 1.44269504f

__device__ __forceinline__ short f2bf(float f) {
  unsigned u = __builtin_bit_cast(unsigned, f);
  u += 0x7fffu + ((u >> 16) & 1u);   // round-to-nearest-even
  return (short)(u >> 16);
}

// ---------------- fused prologue (round-2 version) ----------------
__global__ __launch_bounds__(256) void gat_pro(
    const float* __restrict__ feat, const float* __restrict__ W,
    const float* __restrict__ a1, const float* __restrict__ a2,
    short* __restrict__ featB, short* __restrict__ WB,
    float* __restrict__ AxL, float* __restrict__ AyL) {
  __shared__ __align__(16) float a1f[256], a2f[256];
  __shared__ __align__(16) float w1f[256], w2f[256];
  __shared__ __align__(16) float tile[32][260];
  const int tid = threadIdx.x;
  const int f = blockIdx.x, b = blockIdx.y;

  a1f[tid] = a1[tid];
  a2f[tid] = a2[tid];
  __syncthreads();

  {
    float s1 = 0.f, s2 = 0.f;
    const float4* wr = (const float4*)(W + (size_t)tid * 256);
    for (int d0 = 0; d0 < 64; ++d0) {
      float4 v = wr[d0];
      s1 += v.x * a1f[d0 * 4] + v.y * a1f[d0 * 4 + 1] + v.z * a1f[d0 * 4 + 2] + v.w * a1f[d0 * 4 + 3];
      s2 += v.x * a2f[d0 * 4] + v.y * a2f[d0 * 4 + 1] + v.z * a2f[d0 * 4 + 2] + v.w * a2f[d0 * 4 + 3];
    }
    w1f[tid] = s1;
    w2f[tid] = s2;
  }
  __syncthreads();

  {
    const int r = tid >> 3, g8 = tid & 7;
    const float* frow = feat + ((size_t)(b * 4096 + f * 32 + r)) * 256;
    float s1 = 0.f, s2 = 0.f;
#pragma unroll
    for (int k = 0; k < 8; ++k) {
      const int c4 = g8 + 8 * k;
      float4 v = *(const float4*)(frow + c4 * 4);
      float4 u1 = *(const float4*)&w1f[c4 * 4];
      float4 u2 = *(const float4*)&w2f[c4 * 4];
      s1 += v.x * u1.x + v.y * u1.y + v.z * u1.z + v.w * u1.w;
      s2 += v.x * u2.x + v.y * u2.y + v.z * u2.z + v.w * u2.w;
      *(float4*)&tile[r][c4 * 4] = v;
    }
#pragma unroll
    for (int off = 4; off >= 1; off >>= 1) {
      s1 += __shfl_xor(s1, off);
      s2 += __shfl_xor(s2, off);
    }
    if (g8 == 0) {
      AxL[b * 4096 + f * 32 + r] = s1 * LOG2E;
      AyL[b * 4096 + f * 32 + r] = s2 * LOG2E;
    }
  }
  __syncthreads();

  {
    const int g = tid >> 4, l15 = tid & 15;
    short* d = featB + (((size_t)((b * 128 + f) * 16 + g)) * 64) * 8;
#pragma unroll
    for (int q = 0; q < 4; ++q) {
      short8 v;
#pragma unroll
      for (int j8 = 0; j8 < 8; ++j8) v[j8] = f2bf(tile[q * 8 + j8][g * 16 + l15]);
      *(short8*)(d + (q * 16 + l15) * 8) = v;
    }
  }

  if (b == 0 && f < 8) {
    const int g = tid >> 4, l15 = tid & 15;
    const float* s = W + ((size_t)f * 32) * 256 + g * 16 + l15;
    short* d = WB + (((size_t)(f * 16 + g)) * 64) * 8;
#pragma unroll
    for (int q = 0; q < 4; ++q) {
      short8 v;
#pragma unroll
      for (int j8 = 0; j8 < 8; ++j8) v[j8] = f2bf(s[(q * 8 + j8) * 256]);
      *(short8*)(d + (q * 16 + l15) * 8) = v;
    }
  }
}

// -------- fused softmax(mask(lrelu(rank1)))@feat @W +ELU --------
// Round-2 structure with the featB 2x-duplication removed: phase 2 waves
// now own 2 column-tiles x ALL 4 row-groups (was 4 col-tiles x 2 rowg, in
// which wave pairs with equal cgrp loaded identical fragments). Every
// featB fragment is loaded exactly once per block: L2->CU featB traffic
// halves (256 -> 128 KB per block per superstep; chip 1 GB -> 0.5 GB),
// attacking the modeled binding pipe (L2 port ~56 B/cyc/CU: featB was
// ~4.6k of the ~14.4k-cycle superstep). Register budget unchanged
// (acc[4][2]+lac[4] == old acc[2][4]+lac[2] x dup); LDS, barrier count,
// P-producer roles and epilogue identical to round 2.
__global__ __launch_bounds__(512, 2) void gat_attn(
    const short* __restrict__ featB,  // [4][128][16][64][8] bf16 fragments
    const int* __restrict__ adj,      // [4][4096][4096]
    const float* __restrict__ AxL, const float* __restrict__ AyL,
    const short* __restrict__ WB,     // [8][16][64][8] bf16 fragments
    float* __restrict__ out)          // [4][4096][256] f32
{
  __shared__ short smem[33792];  // Pbuf[2][64][264]; later aliased as hbuf[64][264]
  __shared__ float mred[8];

  const int tid = threadIdx.x;
  const int blk = blockIdx.x;
  const int x = blk & 7;
  const int b = x >> 1;                       // XCD-pinned batch
  const int it = ((blk >> 3) << 1) | (x & 1); // 0..63
  const int i0 = it << 6;
  const int scoff = (blk >> 3) & 15;          // staggered j-window start

  const int lane = tid & 63;
  const int aw = tid >> 6;                    // wave 0..7

  // ---- per-batch max of AxL ----
  const float* axb = AxL + b * 4096;
  float mx = -3.4e38f;
  for (int i = tid; i < 4096; i += 512) mx = fmaxf(mx, axb[i]);
#pragma unroll
  for (int off = 32; off >= 1; off >>= 1) mx = fmaxf(mx, __shfl_xor(mx, off));
  if (lane == 0) mred[aw] = mx;
  __syncthreads();
  const float MbLb = fmaxf(fmaxf(fmaxf(mred[0], mred[1]), fmaxf(mred[2], mred[3])),
                           fmaxf(fmaxf(mred[4], mred[5]), fmaxf(mred[6], mred[7])));

  // --- P-producer role: wave owns rows aw*8..aw*8+7; lane owns 4 j's ---
  float aLk[8], ddk[8];
#pragma unroll
  for (int k = 0; k < 8; ++k) {
    float ayL = AyL[b * 4096 + i0 + aw * 8 + k];
    float sL = ayL + MbLb;
    float mrL = fmaxf(sL, 0.2f * sL);
    aLk[k] = ayL - mrL;
    ddk[k] = -0.8f * mrL;
  }
  const int* adjr = adj + ((size_t)(b * 4096 + i0 + aw * 8)) * 4096 + lane * 4;
  const float4* axp = (const float4*)(AxL + b * 4096) + lane;

  // --- MFMA role: wave owns col-tiles g in {2*aw, 2*aw+1}, all 4 row-groups ---
  const int cg2 = aw << 1;
  const int l15 = lane & 15;
  const int q = lane >> 4;

  f32x4 acc[4][2], lac[4];
#pragma unroll
  for (int r = 0; r < 4; ++r) {
    lac[r] = (f32x4){0.f, 0.f, 0.f, 0.f};
#pragma unroll
    for (int j = 0; j < 2; ++j) acc[r][j] = (f32x4){0.f, 0.f, 0.f, 0.f};
  }

  short8 ones;
#pragma unroll
  for (int j = 0; j < 8; ++j) ones[j] = (short)0x3F80;  // bf16 1.0

  const short* fbb = featB + (size_t)b * 128 * 16 * 64 * 8 + lane * 8;

  i32x4 adv[8];
  float4 axv;
  {
    const int w0 = scoff;
    axv = axp[w0 * 64];
#pragma unroll
    for (int k = 0; k < 8; ++k)
      adv[k] = __builtin_nontemporal_load((const i32x4*)(adjr) + (size_t)k * 1024 + w0 * 64);
  }

  for (int sc = 0; sc < 16; ++sc) {
    const int wsc = (scoff + sc) & 15;        // actual j-window this iteration
    const int pb = (sc & 1) * 16896;
    // ---- phase 1: 32 probs (8 rows x 4 j) -> Pbuf ----
    {
      const float* af = (const float*)&axv;
#pragma unroll
      for (int k = 0; k < 8; ++k) {
        unsigned pr[4];
#pragma unroll
        for (int u = 0; u < 4; ++u) {
          float v = af[u] + aLk[k];
          float uu = fmaxf(v, fmaf(0.2f, v, ddk[k]));
          unsigned ub = adv[k][u] > 0 ? __builtin_bit_cast(unsigned, uu) : 0xFF800000u;
          float p = __builtin_amdgcn_exp2f(__builtin_bit_cast(float, ub));
          pr[u] = __builtin_bit_cast(unsigned, p) + 0x8000u;
        }
        u32x2 pw;
        pw[0] = __builtin_amdgcn_perm(pr[1], pr[0], 0x07060302u);
        pw[1] = __builtin_amdgcn_perm(pr[3], pr[2], 0x07060302u);
        *(u32x2*)(smem + pb + (aw * 8 + k) * 264 + lane * 4) = pw;
      }
    }
    __syncthreads();

    // ---- prefetch next super-chunk's adj (contiguous 1 KB/instr) + Ax ----
    if (sc < 15) {
      const int wn = (scoff + sc + 1) & 15;
      axv = axp[wn * 64];
#pragma unroll
      for (int k = 0; k < 8; ++k)
        adv[k] = __builtin_nontemporal_load((const i32x4*)(adjr) + (size_t)k * 1024 + wn * 64);
    }

    // ---- phase 2: 8 k-steps; wave: 2 col-tiles x 4 row-groups, each
    //      featB fragment loaded exactly once per block ----
#pragma unroll
    for (int h = 0; h < 8; ++h) {
      const int f = wsc * 8 + h;
      const short* fb = fbb + (((size_t)f * 16 + cg2) << 9);
      short8 a[4];
#pragma unroll
      for (int r = 0; r < 4; ++r)
        a[r] = *(const short8*)(smem + pb + (r * 16 + l15) * 264 + h * 32 + q * 8);
#pragma unroll
      for (int r = 0; r < 4; ++r)
        lac[r] = __builtin_amdgcn_mfma_f32_16x16x32_bf16(a[r], ones, lac[r], 0, 0, 0);
#pragma unroll
      for (int ct = 0; ct < 2; ++ct) {
        short8 bf = *(const short8*)(fb + (ct << 9));
#pragma unroll
        for (int r = 0; r < 4; ++r)
          acc[r][ct] = __builtin_amdgcn_mfma_f32_16x16x32_bf16(a[r], bf, acc[r][ct], 0, 0, 0);
      }
    }
  }

  // lac[r][reg] = row-sum for row r*16 + q*4 + reg (C/D layout)
  float linv[4][4];
#pragma unroll
  for (int r = 0; r < 4; ++r)
#pragma unroll
    for (int reg = 0; reg < 4; ++reg) {
      float l = lac[r][reg];
      linv[r][reg] = l > 0.f ? 1.f / l : 0.f;
    }

  __syncthreads();   // all Pbuf reads done before aliasing smem as hbuf
  short* hbuf = smem;  // [64][264]
#pragma unroll
  for (int r = 0; r < 4; ++r)
#pragma unroll
    for (int reg = 0; reg < 4; ++reg) {
      const int lr = r * 16 + q * 4 + reg;
#pragma unroll
      for (int ct = 0; ct < 2; ++ct)
        hbuf[lr * 264 + (cg2 + ct) * 16 + l15] = f2bf(acc[r][ct][reg] * linv[r][reg]);
    }
  __syncthreads();

  // ---- epilogue GEMM: (64x256) @ W, ELU, store (round-2 roles) ----
  const int rowg = (aw & 1) << 4;    // 0/16; second group is +32
  const int cgrp = (aw >> 1) << 2;   // col-group base in 16-col units

  f32x4 ac2[2][4];
#pragma unroll
  for (int r = 0; r < 2; ++r)
#pragma unroll
    for (int j = 0; j < 4; ++j) ac2[r][j] = (f32x4){0.f, 0.f, 0.f, 0.f};

  const short* wbb = WB + lane * 8;
#pragma unroll
  for (int f = 0; f < 8; ++f) {
    short8 a0 = *(const short8*)&hbuf[(rowg + l15) * 264 + f * 32 + q * 8];
    short8 a1 = *(const short8*)&hbuf[(rowg + 32 + l15) * 264 + f * 32 + q * 8];
    const short* wb = wbb + (((size_t)f * 16 + cgrp) << 9);
#pragma unroll
    for (int ct = 0; ct < 4; ++ct) {
      short8 bf = *(const short8*)(wb + (ct << 9));
      ac2[0][ct] = __builtin_amdgcn_mfma_f32_16x16x32_bf16(a0, bf, ac2[0][ct], 0, 0, 0);
      ac2[1][ct] = __builtin_amdgcn_mfma_f32_16x16x32_bf16(a1, bf, ac2[1][ct], 0, 0, 0);
    }
  }

#pragma unroll
  for (int r = 0; r < 2; ++r)
#pragma unroll
    for (int reg = 0; reg < 4; ++reg) {
      const int row = i0 + rowg + r * 32 + q * 4 + reg;
      float* orow = out + ((size_t)(b * 4096 + row)) * 256 + cgrp * 16 + l15;
#pragma unroll
      for (int ct = 0; ct < 4; ++ct) {
        float v = ac2[r][ct][reg];
        float o = v > 0.f ? v : (__builtin_amdgcn_exp2f(v * LOG2E) - 1.f);
        __builtin_nontemporal_store(o, orow + ct * 16);
      }
    }
}

extern "C" void kernel_launch(void* const* d_in, const int* in_sizes, int n_in,
                              void* d_out, int out_size, void* d_ws, size_t ws_size,
                              hipStream_t stream) {
  (void)in_sizes; (void)n_in; (void)out_size; (void)ws_size;
  const float* feat = (const float*)d_in[0];
  const int* adj = (const int*)d_in[1];
  const float* W = (const float*)d_in[2];
  const float* a1 = (const float*)d_in[3];
  const float* a2 = (const float*)d_in[4];
  float* out = (float*)d_out;

  char* ws = (char*)d_ws;
  short* featB   = (short*)ws;                     // 4*128*16*64*8*2 = 8,388,608 B
  short* WB      = (short*)(ws + 8388608);         // 131,072 B
  float* AxL     = (float*)(ws + 8519680);         // 64 KB
  float* AyL     = (float*)(ws + 8585216);         // 64 KB

  hipLaunchKernelGGL(gat_pro, dim3(128, 4), dim3(256), 0, stream, feat, W, a1, a2, featB, WB, AxL, AyL);
  hipLaunchKernelGGL(gat_attn, dim3(256), dim3(512), 0, stream, featB, adj, AxL, AyL, WB, out);
}

// Round 7
// 409.718 us; speedup vs baseline: 1.2361x; 1.0008x over previous
//
#include <hip/hip_runtime.h>

typedef __attribute__((ext_vector_type(8))) short short8;
typedef __attribute__((ext_vector_type(4))) float f32x4;
typedef __attribute__((ext_vector_type(4))) int i32x4;
typedef __attribute__((ext_vector_type(2))) unsigned u32x2;

#define LOG2E 1.44269504f

__device__ __forceinline__ short f2bf(float f) {
  unsigned u = __builtin_bit_cast(unsigned, f);
  u += 0x7fffu + ((u >> 16) & 1u);   // round-to-nearest-even
  return (short)(u >> 16);
}

// ---------------- fused prologue (round-2 version) ----------------
__global__ __launch_bounds__(256) void gat_pro(
    const float* __restrict__ feat, const float* __restrict__ W,
    const float* __restrict__ a1, const float* __restrict__ a2,
    short* __restrict__ featB, short* __restrict__ WB,
    float* __restrict__ AxL, float* __restrict__ AyL) {
  __shared__ __align__(16) float a1f[256], a2f[256];
  __shared__ __align__(16) float w1f[256], w2f[256];
  __shared__ __align__(16) float tile[32][260];
  const int tid = threadIdx.x;
  const int f = blockIdx.x, b = blockIdx.y;

  a1f[tid] = a1[tid];
  a2f[tid] = a2[tid];
  __syncthreads();

  {
    float s1 = 0.f, s2 = 0.f;
    const float4* wr = (const float4*)(W + (size_t)tid * 256);
    for (int d0 = 0; d0 < 64; ++d0) {
      float4 v = wr[d0];
      s1 += v.x * a1f[d0 * 4] + v.y * a1f[d0 * 4 + 1] + v.z * a1f[d0 * 4 + 2] + v.w * a1f[d0 * 4 + 3];
      s2 += v.x * a2f[d0 * 4] + v.y * a2f[d0 * 4 + 1] + v.z * a2f[d0 * 4 + 2] + v.w * a2f[d0 * 4 + 3];
    }
    w1f[tid] = s1;
    w2f[tid] = s2;
  }
  __syncthreads();

  {
    const int r = tid >> 3, g8 = tid & 7;
    const float* frow = feat + ((size_t)(b * 4096 + f * 32 + r)) * 256;
    float s1 = 0.f, s2 = 0.f;
#pragma unroll
    for (int k = 0; k < 8; ++k) {
      const int c4 = g8 + 8 * k;
      float4 v = *(const float4*)(frow + c4 * 4);
      float4 u1 = *(const float4*)&w1f[c4 * 4];
      float4 u2 = *(const float4*)&w2f[c4 * 4];
      s1 += v.x * u1.x + v.y * u1.y + v.z * u1.z + v.w * u1.w;
      s2 += v.x * u2.x + v.y * u2.y + v.z * u2.z + v.w * u2.w;
      *(float4*)&tile[r][c4 * 4] = v;
    }
#pragma unroll
    for (int off = 4; off >= 1; off >>= 1) {
      s1 += __shfl_xor(s1, off);
      s2 += __shfl_xor(s2, off);
    }
    if (g8 == 0) {
      AxL[b * 4096 + f * 32 + r] = s1 * LOG2E;
      AyL[b * 4096 + f * 32 + r] = s2 * LOG2E;
    }
  }
  __syncthreads();

  {
    const int g = tid >> 4, l15 = tid & 15;
    short* d = featB + (((size_t)((b * 128 + f) * 16 + g)) * 64) * 8;
#pragma unroll
    for (int q = 0; q < 4; ++q) {
      short8 v;
#pragma unroll
      for (int j8 = 0; j8 < 8; ++j8) v[j8] = f2bf(tile[q * 8 + j8][g * 16 + l15]);
      *(short8*)(d + (q * 16 + l15) * 8) = v;
    }
  }

  if (b == 0 && f < 8) {
    const int g = tid >> 4, l15 = tid & 15;
    const float* s = W + ((size_t)f * 32) * 256 + g * 16 + l15;
    short* d = WB + (((size_t)(f * 16 + g)) * 64) * 8;
#pragma unroll
    for (int q = 0; q < 4; ++q) {
      short8 v;
#pragma unroll
      for (int j8 = 0; j8 < 8; ++j8) v[j8] = f2bf(s[(q * 8 + j8) * 256]);
      *(short8*)(d + (q * 16 + l15) * 8) = v;
    }
  }
}

// -------- fused softmax(mask(lrelu(rank1)))@feat @W +ELU --------
// Round-6 structure (featB dedup: wave = 2 col-tiles x 4 row-groups) plus
// STAGGERED 2-DEEP adj prefetch: window sc+2's loads issue in sc's phase-2
// slot -> each load streams over ~2 supersteps instead of one ~2k-cycle
// phase-2 window (64 KB/CU/superstep needs ~6.5k cyc at fair-share HBM BW;
// 1-deep prefetch left phase1 stalled ~4.5k cyc on vmcnt). Requires the
// in-loop barrier to NOT drain vmcnt: raw s_barrier + lgkmcnt(0) (LDS
// visibility only; adj/featB loads are same-wave-consumed). __syncthreads'
// compiler-emitted vmcnt(0) drain is exactly what regressed round 3.
// advE/advO named buffers + sc-loop unrolled 2x -> static reg indexing.
__global__ __launch_bounds__(512, 2) void gat_attn(
    const short* __restrict__ featB,  // [4][128][16][64][8] bf16 fragments
    const int* __restrict__ adj,      // [4][4096][4096]
    const float* __restrict__ AxL, const float* __restrict__ AyL,
    const short* __restrict__ WB,     // [8][16][64][8] bf16 fragments
    float* __restrict__ out)          // [4][4096][256] f32
{
  __shared__ short smem[33792];  // Pbuf[2][64][264]; later aliased as hbuf[64][264]
  __shared__ float mred[8];

  const int tid = threadIdx.x;
  const int blk = blockIdx.x;
  const int x = blk & 7;
  const int b = x >> 1;                       // XCD-pinned batch
  const int it = ((blk >> 3) << 1) | (x & 1); // 0..63
  const int i0 = it << 6;
  const int scoff = (blk >> 3) & 15;          // staggered j-window start

  const int lane = tid & 63;
  const int aw = tid >> 6;                    // wave 0..7

  // ---- per-batch max of AxL ----
  const float* axb = AxL + b * 4096;
  float mx = -3.4e38f;
  for (int i = tid; i < 4096; i += 512) mx = fmaxf(mx, axb[i]);
#pragma unroll
  for (int off = 32; off >= 1; off >>= 1) mx = fmaxf(mx, __shfl_xor(mx, off));
  if (lane == 0) mred[aw] = mx;
  __syncthreads();
  const float MbLb = fmaxf(fmaxf(fmaxf(mred[0], mred[1]), fmaxf(mred[2], mred[3])),
                           fmaxf(fmaxf(mred[4], mred[5]), fmaxf(mred[6], mred[7])));

  // --- P-producer role: wave owns rows aw*8..aw*8+7; lane owns 4 j's ---
  float aLk[8], ddk[8];
#pragma unroll
  for (int k = 0; k < 8; ++k) {
    float ayL = AyL[b * 4096 + i0 + aw * 8 + k];
    float sL = ayL + MbLb;
    float mrL = fmaxf(sL, 0.2f * sL);
    aLk[k] = ayL - mrL;
    ddk[k] = -0.8f * mrL;
  }
  const int* adjr = adj + ((size_t)(b * 4096 + i0 + aw * 8)) * 4096 + lane * 4;
  const float4* axp = (const float4*)(AxL + b * 4096) + lane;

  // --- MFMA role: wave owns col-tiles g in {2*aw, 2*aw+1}, all 4 row-groups ---
  const int cg2 = aw << 1;
  const int l15 = lane & 15;
  const int q = lane >> 4;

  f32x4 acc[4][2], lac[4];
#pragma unroll
  for (int r = 0; r < 4; ++r) {
    lac[r] = (f32x4){0.f, 0.f, 0.f, 0.f};
#pragma unroll
    for (int j = 0; j < 2; ++j) acc[r][j] = (f32x4){0.f, 0.f, 0.f, 0.f};
  }

  short8 ones;
#pragma unroll
  for (int j = 0; j < 8; ++j) ones[j] = (short)0x3F80;  // bf16 1.0

  const short* fbb = featB + (size_t)b * 128 * 16 * 64 * 8 + lane * 8;

  i32x4 advE[8], advO[8];
  float4 axvE, axvO;

  // phase 1 for superstep sc using window data advU/axvU
  auto phase1 = [&](int sc, const i32x4 (&advU)[8], const float4& axvU) {
    const int pb = (sc & 1) * 16896;
    const float* af = (const float*)&axvU;
#pragma unroll
    for (int k = 0; k < 8; ++k) {
      unsigned pr[4];
#pragma unroll
      for (int u = 0; u < 4; ++u) {
        float v = af[u] + aLk[k];
        float uu = fmaxf(v, fmaf(0.2f, v, ddk[k]));
        unsigned ub = advU[k][u] > 0 ? __builtin_bit_cast(unsigned, uu) : 0xFF800000u;
        float p = __builtin_amdgcn_exp2f(__builtin_bit_cast(float, ub));
        pr[u] = __builtin_bit_cast(unsigned, p) + 0x8000u;
      }
      u32x2 pw;
      pw[0] = __builtin_amdgcn_perm(pr[1], pr[0], 0x07060302u);
      pw[1] = __builtin_amdgcn_perm(pr[3], pr[2], 0x07060302u);
      *(u32x2*)(smem + pb + (aw * 8 + k) * 264 + lane * 4) = pw;
    }
  };

  // phase 2 for superstep sc (8 k-steps; fragment loaded once per block)
  auto phase2 = [&](int sc) {
    const int wsc = (scoff + sc) & 15;
    const int pb = (sc & 1) * 16896;
#pragma unroll
    for (int h = 0; h < 8; ++h) {
      const int f = wsc * 8 + h;
      const short* fb = fbb + (((size_t)f * 16 + cg2) << 9);
      short8 a[4];
#pragma unroll
      for (int r = 0; r < 4; ++r)
        a[r] = *(const short8*)(smem + pb + (r * 16 + l15) * 264 + h * 32 + q * 8);
#pragma unroll
      for (int r = 0; r < 4; ++r)
        lac[r] = __builtin_amdgcn_mfma_f32_16x16x32_bf16(a[r], ones, lac[r], 0, 0, 0);
#pragma unroll
      for (int ct = 0; ct < 2; ++ct) {
        short8 bf = *(const short8*)(fb + (ct << 9));
#pragma unroll
        for (int r = 0; r < 4; ++r)
          acc[r][ct] = __builtin_amdgcn_mfma_f32_16x16x32_bf16(a[r], bf, acc[r][ct], 0, 0, 0);
      }
    }
  };

  // ---- pre-loop: 2-deep prefetch of windows scoff, scoff+1 ----
  {
    const int w0 = scoff, w1 = (scoff + 1) & 15;
    axvE = axp[w0 * 64];
#pragma unroll
    for (int k = 0; k < 8; ++k)
      advE[k] = __builtin_nontemporal_load((const i32x4*)(adjr) + (size_t)k * 1024 + w0 * 64);
    axvO = axp[w1 * 64];
#pragma unroll
    for (int k = 0; k < 8; ++k)
      advO[k] = __builtin_nontemporal_load((const i32x4*)(adjr) + (size_t)k * 1024 + w1 * 64);
  }

  // ---- main loop, unrolled 2x; raw barrier (no vmcnt drain) ----
  for (int scp = 0; scp < 8; ++scp) {
    {
      const int sc = 2 * scp;           // even: uses E buffers
      phase1(sc, advE, axvE);
      asm volatile("s_waitcnt lgkmcnt(0)" ::: "memory");
      __builtin_amdgcn_s_barrier();
      if (sc < 14) {
        const int wn = (scoff + sc + 2) & 15;
        axvE = axp[wn * 64];
#pragma unroll
        for (int k = 0; k < 8; ++k)
          advE[k] = __builtin_nontemporal_load((const i32x4*)(adjr) + (size_t)k * 1024 + wn * 64);
      }
      phase2(sc);
    }
    {
      const int sc = 2 * scp + 1;       // odd: uses O buffers
      phase1(sc, advO, axvO);
      asm volatile("s_waitcnt lgkmcnt(0)" ::: "memory");
      __builtin_amdgcn_s_barrier();
      if (sc < 14) {
        const int wn = (scoff + sc + 2) & 15;
        axvO = axp[wn * 64];
#pragma unroll
        for (int k = 0; k < 8; ++k)
          advO[k] = __builtin_nontemporal_load((const i32x4*)(adjr) + (size_t)k * 1024 + wn * 64);
      }
      phase2(sc);
    }
  }

  // lac[r][reg] = row-sum for row r*16 + q*4 + reg (C/D layout)
  float linv[4][4];
#pragma unroll
  for (int r = 0; r < 4; ++r)
#pragma unroll
    for (int reg = 0; reg < 4; ++reg) {
      float l = lac[r][reg];
      linv[r][reg] = l > 0.f ? 1.f / l : 0.f;
    }

  __syncthreads();   // full barrier (incl. drain) before aliasing smem as hbuf
  short* hbuf = smem;  // [64][264]
#pragma unroll
  for (int r = 0; r < 4; ++r)
#pragma unroll
    for (int reg = 0; reg < 4; ++reg) {
      const int lr = r * 16 + q * 4 + reg;
#pragma unroll
      for (int ct = 0; ct < 2; ++ct)
        hbuf[lr * 264 + (cg2 + ct) * 16 + l15] = f2bf(acc[r][ct][reg] * linv[r][reg]);
    }
  __syncthreads();

  // ---- epilogue GEMM: (64x256) @ W, ELU, store (round-2 roles) ----
  const int rowg = (aw & 1) << 4;    // 0/16; second group is +32
  const int cgrp = (aw >> 1) << 2;   // col-group base in 16-col units

  f32x4 ac2[2][4];
#pragma unroll
  for (int r = 0; r < 2; ++r)
#pragma unroll
    for (int j = 0; j < 4; ++j) ac2[r][j] = (f32x4){0.f, 0.f, 0.f, 0.f};

  const short* wbb = WB + lane * 8;
#pragma unroll
  for (int f = 0; f < 8; ++f) {
    short8 a0 = *(const short8*)&hbuf[(rowg + l15) * 264 + f * 32 + q * 8];
    short8 a1 = *(const short8*)&hbuf[(rowg + 32 + l15) * 264 + f * 32 + q * 8];
    const short* wb = wbb + (((size_t)f * 16 + cgrp) << 9);
#pragma unroll
    for (int ct = 0; ct < 4; ++ct) {
      short8 bf = *(const short8*)(wb + (ct << 9));
      ac2[0][ct] = __builtin_amdgcn_mfma_f32_16x16x32_bf16(a0, bf, ac2[0][ct], 0, 0, 0);
      ac2[1][ct] = __builtin_amdgcn_mfma_f32_16x16x32_bf16(a1, bf, ac2[1][ct], 0, 0, 0);
    }
  }

#pragma unroll
  for (int r = 0; r < 2; ++r)
#pragma unroll
    for (int reg = 0; reg < 4; ++reg) {
      const int row = i0 + rowg + r * 32 + q * 4 + reg;
      float* orow = out + ((size_t)(b * 4096 + row)) * 256 + cgrp * 16 + l15;
#pragma unroll
      for (int ct = 0; ct < 4; ++ct) {
        float v = ac2[r][ct][reg];
        float o = v > 0.f ? v : (__builtin_amdgcn_exp2f(v * LOG2E) - 1.f);
        __builtin_nontemporal_store(o, orow + ct * 16);
      }
    }
}

extern "C" void kernel_launch(void* const* d_in, const int* in_sizes, int n_in,
                              void* d_out, int out_size, void* d_ws, size_t ws_size,
                              hipStream_t stream) {
  (void)in_sizes; (void)n_in; (void)out_size; (void)ws_size;
  const float* feat = (const float*)d_in[0];
  const int* adj = (const int*)d_in[1];
  const float* W = (const float*)d_in[2];
  const float* a1 = (const float*)d_in[3];
  const float* a2 = (const float*)d_in[4];
  float* out = (float*)d_out;

  char* ws = (char*)d_ws;
  short* featB   = (short*)ws;                     // 4*128*16*64*8*2 = 8,388,608 B
  short* WB      = (short*)(ws + 8388608);         // 131,072 B
  float* AxL     = (float*)(ws + 8519680);         // 64 KB
  float* AyL     = (float*)(ws + 8585216);         // 64 KB

  hipLaunchKernelGGL(gat_pro, dim3(128, 4), dim3(256), 0, stream, feat, W, a1, a2, featB, WB, AxL, AyL);
  hipLaunchKernelGGL(gat_attn, dim3(256), dim3(512), 0, stream, featB, adj, AxL, AyL, WB, out);
}

// Round 8
// 406.799 us; speedup vs baseline: 1.2449x; 1.0072x over previous
//
#include <hip/hip_runtime.h>

typedef __attribute__((ext_vector_type(8))) short short8;
typedef __attribute__((ext_vector_type(4))) float f32x4;
typedef __attribute__((ext_vector_type(4))) int i32x4;
typedef __attribute__((ext_vector_type(2))) unsigned u32x2;

#define LOG2E 1.44269504f

__device__ __forceinline__ short f2bf(float f) {
  unsigned u = __builtin_bit_cast(unsigned, f);
  u += 0x7fffu + ((u >> 16) & 1u);   // round-to-nearest-even
  return (short)(u >> 16);
}

// ---------------- fused prologue (round-2 version) ----------------
__global__ __launch_bounds__(256) void gat_pro(
    const float* __restrict__ feat, const float* __restrict__ W,
    const float* __restrict__ a1, const float* __restrict__ a2,
    short* __restrict__ featB, short* __restrict__ WB,
    float* __restrict__ AxL, float* __restrict__ AyL) {
  __shared__ __align__(16) float a1f[256], a2f[256];
  __shared__ __align__(16) float w1f[256], w2f[256];
  __shared__ __align__(16) float tile[32][260];
  const int tid = threadIdx.x;
  const int f = blockIdx.x, b = blockIdx.y;

  a1f[tid] = a1[tid];
  a2f[tid] = a2[tid];
  __syncthreads();

  {
    float s1 = 0.f, s2 = 0.f;
    const float4* wr = (const float4*)(W + (size_t)tid * 256);
    for (int d0 = 0; d0 < 64; ++d0) {
      float4 v = wr[d0];
      s1 += v.x * a1f[d0 * 4] + v.y * a1f[d0 * 4 + 1] + v.z * a1f[d0 * 4 + 2] + v.w * a1f[d0 * 4 + 3];
      s2 += v.x * a2f[d0 * 4] + v.y * a2f[d0 * 4 + 1] + v.z * a2f[d0 * 4 + 2] + v.w * a2f[d0 * 4 + 3];
    }
    w1f[tid] = s1;
    w2f[tid] = s2;
  }
  __syncthreads();

  {
    const int r = tid >> 3, g8 = tid & 7;
    const float* frow = feat + ((size_t)(b * 4096 + f * 32 + r)) * 256;
    float s1 = 0.f, s2 = 0.f;
#pragma unroll
    for (int k = 0; k < 8; ++k) {
      const int c4 = g8 + 8 * k;
      float4 v = *(const float4*)(frow + c4 * 4);
      float4 u1 = *(const float4*)&w1f[c4 * 4];
      float4 u2 = *(const float4*)&w2f[c4 * 4];
      s1 += v.x * u1.x + v.y * u1.y + v.z * u1.z + v.w * u1.w;
      s2 += v.x * u2.x + v.y * u2.y + v.z * u2.z + v.w * u2.w;
      *(float4*)&tile[r][c4 * 4] = v;
    }
#pragma unroll
    for (int off = 4; off >= 1; off >>= 1) {
      s1 += __shfl_xor(s1, off);
      s2 += __shfl_xor(s2, off);
    }
    if (g8 == 0) {
      AxL[b * 4096 + f * 32 + r] = s1 * LOG2E;
      AyL[b * 4096 + f * 32 + r] = s2 * LOG2E;
    }
  }
  __syncthreads();

  {
    const int g = tid >> 4, l15 = tid & 15;
    short* d = featB + (((size_t)((b * 128 + f) * 16 + g)) * 64) * 8;
#pragma unroll
    for (int q = 0; q < 4; ++q) {
      short8 v;
#pragma unroll
      for (int j8 = 0; j8 < 8; ++j8) v[j8] = f2bf(tile[q * 8 + j8][g * 16 + l15]);
      *(short8*)(d + (q * 16 + l15) * 8) = v;
    }
  }

  if (b == 0 && f < 8) {
    const int g = tid >> 4, l15 = tid & 15;
    const float* s = W + ((size_t)f * 32) * 256 + g * 16 + l15;
    short* d = WB + (((size_t)(f * 16 + g)) * 64) * 8;
#pragma unroll
    for (int q = 0; q < 4; ++q) {
      short8 v;
#pragma unroll
      for (int j8 = 0; j8 < 8; ++j8) v[j8] = f2bf(s[(q * 8 + j8) * 256]);
      *(short8*)(d + (q * 16 + l15) * 8) = v;
    }
  }
}

// -------- fused softmax(mask(lrelu(rank1)))@feat @W +ELU --------
// Round-6 structure (featB dedup) + REGISTER-PREFETCHED featB: fbr[8][2]
// holds the NEXT superstep's fragments; phase2 consumes fbr and reissues
// each register's load for window sc+1 immediately after its MFMAs, so
// every featB load has a full superstep (phase1+barrier+phase2) to
// complete -> phase2's MFMA stream runs without vmem waits. (Round-4
// bitmask experiment proved attn is NOT adj-BW-bound; round-6 dedup
// (-19us) proved featB loads are on the critical path.) Requires raw
// s_barrier + lgkmcnt(0) in-loop (no vmcnt drain: fbr loads are in
// flight across barriers). adv prefetch back to 1-deep (round 7: depth-2
// neutral) to keep VGPR ~210 < 256 (no spill at launch_bounds(512,2)).
__global__ __launch_bounds__(512, 2) void gat_attn(
    const short* __restrict__ featB,  // [4][128][16][64][8] bf16 fragments
    const int* __restrict__ adj,      // [4][4096][4096]
    const float* __restrict__ AxL, const float* __restrict__ AyL,
    const short* __restrict__ WB,     // [8][16][64][8] bf16 fragments
    float* __restrict__ out)          // [4][4096][256] f32
{
  __shared__ short smem[33792];  // Pbuf[2][64][264]; later aliased as hbuf[64][264]
  __shared__ float mred[8];

  const int tid = threadIdx.x;
  const int blk = blockIdx.x;
  const int x = blk & 7;
  const int b = x >> 1;                       // XCD-pinned batch
  const int it = ((blk >> 3) << 1) | (x & 1); // 0..63
  const int i0 = it << 6;
  const int scoff = (blk >> 3) & 15;          // staggered j-window start

  const int lane = tid & 63;
  const int aw = tid >> 6;                    // wave 0..7

  // ---- per-batch max of AxL ----
  const float* axb = AxL + b * 4096;
  float mx = -3.4e38f;
  for (int i = tid; i < 4096; i += 512) mx = fmaxf(mx, axb[i]);
#pragma unroll
  for (int off = 32; off >= 1; off >>= 1) mx = fmaxf(mx, __shfl_xor(mx, off));
  if (lane == 0) mred[aw] = mx;
  __syncthreads();
  const float MbLb = fmaxf(fmaxf(fmaxf(mred[0], mred[1]), fmaxf(mred[2], mred[3])),
                           fmaxf(fmaxf(mred[4], mred[5]), fmaxf(mred[6], mred[7])));

  // --- P-producer role: wave owns rows aw*8..aw*8+7; lane owns 4 j's ---
  float aLk[8], ddk[8];
#pragma unroll
  for (int k = 0; k < 8; ++k) {
    float ayL = AyL[b * 4096 + i0 + aw * 8 + k];
    float sL = ayL + MbLb;
    float mrL = fmaxf(sL, 0.2f * sL);
    aLk[k] = ayL - mrL;
    ddk[k] = -0.8f * mrL;
  }
  const int* adjr = adj + ((size_t)(b * 4096 + i0 + aw * 8)) * 4096 + lane * 4;
  const float4* axp = (const float4*)(AxL + b * 4096) + lane;

  // --- MFMA role: wave owns col-tiles g in {2*aw, 2*aw+1}, all 4 row-groups ---
  const int cg2 = aw << 1;
  const int l15 = lane & 15;
  const int q = lane >> 4;

  f32x4 acc[4][2], lac[4];
#pragma unroll
  for (int r = 0; r < 4; ++r) {
    lac[r] = (f32x4){0.f, 0.f, 0.f, 0.f};
#pragma unroll
    for (int j = 0; j < 2; ++j) acc[r][j] = (f32x4){0.f, 0.f, 0.f, 0.f};
  }

  short8 ones;
#pragma unroll
  for (int j = 0; j < 8; ++j) ones[j] = (short)0x3F80;  // bf16 1.0

  const short* fbb = featB + (size_t)b * 128 * 16 * 64 * 8 + lane * 8;

  i32x4 adv[8];
  float4 axv;
  short8 fbr[8][2];   // next-superstep featB fragments (64 VGPR)

  // ---- pre-loop: adj/Ax window scoff + featB fragments for window scoff ----
  {
    axv = axp[scoff * 64];
#pragma unroll
    for (int k = 0; k < 8; ++k)
      adv[k] = __builtin_nontemporal_load((const i32x4*)(adjr) + (size_t)k * 1024 + scoff * 64);
#pragma unroll
    for (int h = 0; h < 8; ++h) {
      const short* fb = fbb + (((size_t)((scoff * 8 + h) * 16 + cg2)) << 9);
#pragma unroll
      for (int ct = 0; ct < 2; ++ct)
        fbr[h][ct] = *(const short8*)(fb + (ct << 9));
    }
  }

  for (int sc = 0; sc < 16; ++sc) {
    const int pb = (sc & 1) * 16896;
    // ---- phase 1: 32 probs (8 rows x 4 j) -> Pbuf ----
    {
      const float* af = (const float*)&axv;
#pragma unroll
      for (int k = 0; k < 8; ++k) {
        unsigned pr[4];
#pragma unroll
        for (int u = 0; u < 4; ++u) {
          float v = af[u] + aLk[k];
          float uu = fmaxf(v, fmaf(0.2f, v, ddk[k]));
          unsigned ub = adv[k][u] > 0 ? __builtin_bit_cast(unsigned, uu) : 0xFF800000u;
          float p = __builtin_amdgcn_exp2f(__builtin_bit_cast(float, ub));
          pr[u] = __builtin_bit_cast(unsigned, p) + 0x8000u;
        }
        u32x2 pw;
        pw[0] = __builtin_amdgcn_perm(pr[1], pr[0], 0x07060302u);
        pw[1] = __builtin_amdgcn_perm(pr[3], pr[2], 0x07060302u);
        *(u32x2*)(smem + pb + (aw * 8 + k) * 264 + lane * 4) = pw;
      }
    }
    asm volatile("s_waitcnt lgkmcnt(0)" ::: "memory");
    __builtin_amdgcn_s_barrier();   // raw: featB/adj loads stay in flight

    // ---- prefetch next window's adj + Ax (1-deep; hidden under phase 2) ----
    if (sc < 15) {
      const int wn = (scoff + sc + 1) & 15;
      axv = axp[wn * 64];
#pragma unroll
      for (int k = 0; k < 8; ++k)
        adv[k] = __builtin_nontemporal_load((const i32x4*)(adjr) + (size_t)k * 1024 + wn * 64);
    }

    // ---- phase 2: consume fbr (loaded last superstep), reload for next ----
    {
      const int wsc = (scoff + sc) & 15;
      const int wnx = (scoff + sc + 1) & 15;   // sc=15 reloads scoff (unused, valid addr)
#pragma unroll
      for (int h = 0; h < 8; ++h) {
        const short* fbn = fbb + (((size_t)((wnx * 8 + h) * 16 + cg2)) << 9);
        short8 a[4];
#pragma unroll
        for (int r = 0; r < 4; ++r)
          a[r] = *(const short8*)(smem + pb + (r * 16 + l15) * 264 + h * 32 + q * 8);
#pragma unroll
        for (int r = 0; r < 4; ++r)
          lac[r] = __builtin_amdgcn_mfma_f32_16x16x32_bf16(a[r], ones, lac[r], 0, 0, 0);
#pragma unroll
        for (int ct = 0; ct < 2; ++ct) {
          short8 bf = fbr[h][ct];
#pragma unroll
          for (int r = 0; r < 4; ++r)
            acc[r][ct] = __builtin_amdgcn_mfma_f32_16x16x32_bf16(a[r], bf, acc[r][ct], 0, 0, 0);
          fbr[h][ct] = *(const short8*)(fbn + (ct << 9));   // reload for sc+1
        }
      }
    }
  }

  // lac[r][reg] = row-sum for row r*16 + q*4 + reg (C/D layout)
  float linv[4][4];
#pragma unroll
  for (int r = 0; r < 4; ++r)
#pragma unroll
    for (int reg = 0; reg < 4; ++reg) {
      float l = lac[r][reg];
      linv[r][reg] = l > 0.f ? 1.f / l : 0.f;
    }

  __syncthreads();   // full barrier (incl. drain) before aliasing smem as hbuf
  short* hbuf = smem;  // [64][264]
#pragma unroll
  for (int r = 0; r < 4; ++r)
#pragma unroll
    for (int reg = 0; reg < 4; ++reg) {
      const int lr = r * 16 + q * 4 + reg;
#pragma unroll
      for (int ct = 0; ct < 2; ++ct)
        hbuf[lr * 264 + (cg2 + ct) * 16 + l15] = f2bf(acc[r][ct][reg] * linv[r][reg]);
    }
  __syncthreads();

  // ---- epilogue GEMM: (64x256) @ W, ELU, store (round-2 roles) ----
  const int rowg = (aw & 1) << 4;    // 0/16; second group is +32
  const int cgrp = (aw >> 1) << 2;   // col-group base in 16-col units

  f32x4 ac2[2][4];
#pragma unroll
  for (int r = 0; r < 2; ++r)
#pragma unroll
    for (int j = 0; j < 4; ++j) ac2[r][j] = (f32x4){0.f, 0.f, 0.f, 0.f};

  const short* wbb = WB + lane * 8;
#pragma unroll
  for (int f = 0; f < 8; ++f) {
    short8 a0 = *(const short8*)&hbuf[(rowg + l15) * 264 + f * 32 + q * 8];
    short8 a1 = *(const short8*)&hbuf[(rowg + 32 + l15) * 264 + f * 32 + q * 8];
    const short* wb = wbb + (((size_t)f * 16 + cgrp) << 9);
#pragma unroll
    for (int ct = 0; ct < 4; ++ct) {
      short8 bf = *(const short8*)(wb + (ct << 9));
      ac2[0][ct] = __builtin_amdgcn_mfma_f32_16x16x32_bf16(a0, bf, ac2[0][ct], 0, 0, 0);
      ac2[1][ct] = __builtin_amdgcn_mfma_f32_16x16x32_bf16(a1, bf, ac2[1][ct], 0, 0, 0);
    }
  }

#pragma unroll
  for (int r = 0; r < 2; ++r)
#pragma unroll
    for (int reg = 0; reg < 4; ++reg) {
      const int row = i0 + rowg + r * 32 + q * 4 + reg;
      float* orow = out + ((size_t)(b * 4096 + row)) * 256 + cgrp * 16 + l15;
#pragma unroll
      for (int ct = 0; ct < 4; ++ct) {
        float v = ac2[r][ct][reg];
        float o = v > 0.f ? v : (__builtin_amdgcn_exp2f(v * LOG2E) - 1.f);
        __builtin_nontemporal_store(o, orow + ct * 16);
      }
    }
}

extern "C" void kernel_launch(void* const* d_in, const int* in_sizes, int n_in,
                              void* d_out, int out_size, void* d_ws, size_t ws_size,
                              hipStream_t stream) {
  (void)in_sizes; (void)n_in; (void)out_size; (void)ws_size;
  const float* feat = (const float*)d_in[0];
  const int* adj = (const int*)d_in[1];
  const float* W = (const float*)d_in[2];
  const float* a1 = (const float*)d_in[3];
  const float* a2 = (const float*)d_in[4];
  float* out = (float*)d_out;

  char* ws = (char*)d_ws;
  short* featB   = (short*)ws;                     // 4*128*16*64*8*2 = 8,388,608 B
  short* WB      = (short*)(ws + 8388608);         // 131,072 B
  float* AxL     = (float*)(ws + 8519680);         // 64 KB
  float* AyL     = (float*)(ws + 8585216);         // 64 KB

  hipLaunchKernelGGL(gat_pro, dim3(128, 4), dim3(256), 0, stream, feat, W, a1, a2, featB, WB, AxL, AyL);
  hipLaunchKernelGGL(gat_attn, dim3(256), dim3(512), 0, stream, featB, adj, AxL, AyL, WB, out);
}